// Round 10
// baseline (394.098 us; speedup 1.0000x reference)
//
#include <hip/hip_runtime.h>
#include <hip/hip_bf16.h>

typedef unsigned short u16;
typedef unsigned int   u32;

#define NB 32
#define CC 64
#define TT 300
#define VV 25
#define OO 128
#define TO 150
#define KT 9
#define MM 7500          // T*V rows per n (gcn GEMM)
#define MT 59            // ceil(7500/128)
#define M2 3750          // T2*V rows per n (tcn/res GEMMs)

typedef short s8v  __attribute__((ext_vector_type(8)));
typedef float f4v  __attribute__((ext_vector_type(4)));
typedef u16  h4v  __attribute__((ext_vector_type(4)));
typedef u16  h8v  __attribute__((ext_vector_type(8)));

__device__ __forceinline__ float b2f(u16 u){
  union { u32 i; float f; } c; c.i = ((u32)u) << 16; return c.f;
}
__device__ __forceinline__ u16 f2b(float f){
  __hip_bfloat16 h = __float2bfloat16(f);
  return *reinterpret_cast<u16*>(&h);
}
__device__ __forceinline__ void async16(const void* g, void* l){
  __builtin_amdgcn_global_load_lds((const __attribute__((address_space(1))) u32*)g,
                                   (__attribute__((address_space(3))) u32*)l, 16, 0, 0);
}

// ---------------- prep: A_sum + zero-page + tcn_w repack + gcn_w/res_w bf16 ----------------
__global__ __launch_bounds__(256) void k_prep(const float* __restrict__ Ap, const float* __restrict__ ei,
                                              const float* __restrict__ tw, const float* __restrict__ gw,
                                              const float* __restrict__ rw,
                                              float* __restrict__ Asum, float* __restrict__ zbuf,
                                              u16* __restrict__ Wq2, u16* __restrict__ gwb,
                                              u16* __restrict__ rwb){
  int idx = blockIdx.x * 256 + threadIdx.x;
  if (idx < VV*VV){
    float s = 0.f;
    for (int p = 0; p < 3; ++p) s += ei[p] * Ap[p*VV*VV + idx];
    Asum[idx] = s;
  }
  if (idx >= 640 && idx < 768) zbuf[idx - 640] = 0.f;   // 512 B zero page
  int w = idx - 1024;
  if (w >= 0 && w < 18*OO*64){
    int kc = w >> 13;
    int r  = w & 8191;
    int o  = r >> 6;
    int j  = r & 63;
    int k  = kc >> 1;
    int i  = (kc & 1)*64 + j;
    Wq2[w] = f2b(tw[o*(OO*KT) + i*KT + k]);   // Wq2[kc][o][j] = tcn_w[o][i][k]
  }
  int w2 = idx - 148480;
  if (w2 >= 0 && w2 < OO*CC) gwb[w2] = f2b(gw[w2]);   // gwb[o][c]
  int w3 = idx - 156672;
  if (w3 >= 0 && w3 < OO*CC) rwb[w3] = f2b(rw[w3]);   // rwb[o][c]
}

// ---------------- gcn: register-direct MFMA agg + MFMA GEMM: M=(t*25+v), N=128 o, K=64 c ----------------
// xg layout: [n][m=t*25+v][o].  LDS = 32 KB; no x staging buffer.
__global__ __launch_bounds__(256, 4) void k_gcnm(const float* __restrict__ x, const float* __restrict__ Asum,
                                                 const u16* __restrict__ gwb, const float* __restrict__ gb,
                                                 u16* __restrict__ xg){
  __shared__ __align__(16) u16 A_lds[128*64];   // 16 KB, XOR-swizzled granules
  __shared__ __align__(16) u16 B_lds[128*64];   // 16 KB, XOR-swizzled granules
  int bx = blockIdx.x;
  int n  = bx / MT;
  int m0 = (bx % MT) * 128;
  int t0 = m0 / VV, r0 = m0 % VV;
  int tid = threadIdx.x;
  int lane = tid & 63, wv = tid >> 6;
  int wm = (wv & 1) * 64, wo = (wv >> 1) * 64;
  int lr = lane & 15, lq = lane >> 4;

  // ---- stage B (gwb, 16 KB) with plain coalesced loads + swizzled ds_write ----
  {
    const u32* g32 = (const u32*)gwb;
    u32* b32 = (u32*)B_lds;
    for (int s = tid; s < 4096; s += 256){
      int row = s >> 5, col = s & 31;
      int g = col >> 2, c2 = col & 3;
      b32[row*32 + ((g ^ (row & 7))*4 + c2)] = g32[s];
    }
  }

  // ---- A_sum^T B-fragments in registers: bfw[wt], lane holds B[w=lr+16wt][v=lq*8+j] ----
  s8v bfw[2];
  #pragma unroll
  for (int wt = 0; wt < 2; ++wt){
    u16 tmp[8];
    int w = lr + 16*wt;
    #pragma unroll
    for (int j = 0; j < 8; ++j){
      int v = lq*8 + j;
      tmp[j] = (w < VV && v < VV) ? f2b(Asum[v*VV + w]) : (u16)0;
    }
    bfw[wt] = *(s8v*)tmp;
  }

  // ---- agg via MFMA with register-direct A: 28 tasks (7 it x 4 ct) over 4 waves ----
  #pragma unroll
  for (int tt = 0; tt < 7; ++tt){
    int tau = tt*4 + wv;
    int it = tau >> 2, ct = tau & 3;
    int t  = t0 + it;
    int c  = ct*16 + lr;
    const float* xp = x + ((size_t)(n*CC + c)*TT + t)*VV + lq*8;
    float4 xa = make_float4(0.f,0.f,0.f,0.f), xb = xa;
    float x24 = 0.f;
    if (t < TT){
      if (lq < 3){
        xa = *(const float4*)xp;
        xb = *(const float4*)(xp + 4);
      } else {
        x24 = xp[0];
      }
    }
    u16 pk[8];
    if (lq < 3){
      pk[0]=f2b(xa.x); pk[1]=f2b(xa.y); pk[2]=f2b(xa.z); pk[3]=f2b(xa.w);
      pk[4]=f2b(xb.x); pk[5]=f2b(xb.y); pk[6]=f2b(xb.z); pk[7]=f2b(xb.w);
    } else {
      pk[0]=f2b(x24); pk[1]=0; pk[2]=0; pk[3]=0; pk[4]=0; pk[5]=0; pk[6]=0; pk[7]=0;
    }
    s8v af = *(s8v*)pk;
    f4v d0 = (f4v)(0.f), d1 = (f4v)(0.f);
    d0 = __builtin_amdgcn_mfma_f32_16x16x32_bf16(af, bfw[0], d0, 0, 0, 0);
    d1 = __builtin_amdgcn_mfma_f32_16x16x32_bf16(af, bfw[1], d1, 0, 0, 0);
    int cb = ct*16 + lq*4;
    int g  = cb >> 3, co = cb & 7;
    int ml0 = it*VV + lr - r0;                    // w = lr
    if (ml0 >= 0 && ml0 < 128){
      u16 q[4];
      #pragma unroll
      for (int rg = 0; rg < 4; ++rg) q[rg] = f2b(d0[rg]);
      *(h4v*)&A_lds[ml0*64 + ((g ^ (ml0 & 7))*8) + co] = *(h4v*)q;
    }
    int w1 = lr + 16;
    int ml1 = it*VV + w1 - r0;
    if (w1 < VV && ml1 >= 0 && ml1 < 128){
      u16 q[4];
      #pragma unroll
      for (int rg = 0; rg < 4; ++rg) q[rg] = f2b(d1[rg]);
      *(h4v*)&A_lds[ml1*64 + ((g ^ (ml1 & 7))*8) + co] = *(h4v*)q;
    }
  }
  __syncthreads();

  // ---- main GEMM: 64m x 64o per wave, K=64 (2 substeps) ----
  f4v acc[4][4];
  #pragma unroll
  for (int mi = 0; mi < 4; ++mi)
    #pragma unroll
    for (int ni = 0; ni < 4; ++ni) acc[mi][ni] = (f4v)(0.f);
  #pragma unroll
  for (int ks = 0; ks < 2; ++ks){
    int p = ((ks*4 + lq) ^ (lane & 7)) * 8;
    s8v af[4], bf[4];
    #pragma unroll
    for (int mi = 0; mi < 4; ++mi)
      af[mi] = *(const s8v*)&A_lds[(wm + mi*16 + lr)*64 + p];
    #pragma unroll
    for (int ni = 0; ni < 4; ++ni)
      bf[ni] = *(const s8v*)&B_lds[(wo + ni*16 + lr)*64 + p];
    #pragma unroll
    for (int mi = 0; mi < 4; ++mi)
      #pragma unroll
      for (int ni = 0; ni < 4; ++ni)
        acc[mi][ni] = __builtin_amdgcn_mfma_f32_16x16x32_bf16(af[mi], bf[ni], acc[mi][ni], 0, 0, 0);
  }

  float bias[4];
  #pragma unroll
  for (int ni = 0; ni < 4; ++ni) bias[ni] = gb[wo + ni*16 + lr];
  #pragma unroll
  for (int mi = 0; mi < 4; ++mi){
    int mr = m0 + wm + mi*16 + lq*4;
    #pragma unroll
    for (int ni = 0; ni < 4; ++ni){
      int o = wo + ni*16 + lr;
      #pragma unroll
      for (int rg = 0; rg < 4; ++rg){
        int m = mr + rg;
        if (m < MM)
          xg[((size_t)n*MM + m)*OO + o] = f2b(acc[mi][ni][rg] + bias[ni]);
      }
    }
  }
}

// ---------------- tcn as MFMA implicit GEMM + fused BN partial stats ----------------
// xt layout: [n][m=t2*25+v][o]; psum/psq[bx][128] partial sums (f32, pre-rounding values)
__global__ __launch_bounds__(256) void k_tcnm(const u16* __restrict__ xg, const u16* __restrict__ Wq2,
                                              const float* __restrict__ tb, const u16* __restrict__ zbuf,
                                              u16* __restrict__ xt, float* __restrict__ psum,
                                              float* __restrict__ psq){
  __shared__ __align__(16) u16 A_lds[128*64];
  __shared__ __align__(16) u16 B_lds[128*64];
  __shared__ float sredS[4][64];
  __shared__ float sredQ[4][64];
  int bx = blockIdx.x;
  int n  = bx / 30;
  int m0 = (bx % 30) * 128;
  int tid = threadIdx.x;
  int lane = tid & 63, wv = tid >> 6;
  int wm = (wv & 1) * 64, wo = (wv >> 1) * 64;
  int lr = lane & 15, lq = lane >> 4;

  int rlow = tid >> 3;
  int gsrc = (tid & 7) ^ (rlow & 7);
  int tid16 = tid * 16;
  int  tbse[4], vr[4]; bool vm[4];
  #pragma unroll
  for (int it = 0; it < 4; ++it){
    int m = m0 + it*32 + rlow;
    vm[it] = (m < M2);
    int t2 = m / VV, v = m - t2*VV;
    tbse[it] = 2*t2 - 4;
    vr[it] = v;
  }
  size_t basen = (size_t)n*MM*OO + (size_t)gsrc*8;

  f4v acc[4][4];
  #pragma unroll
  for (int mi = 0; mi < 4; ++mi)
    #pragma unroll
    for (int ni = 0; ni < 4; ++ni) acc[mi][ni] = (f4v)(0.f);

  for (int kc = 0; kc < 18; ++kc){
    int k  = kc >> 1;
    int i0 = (kc & 1) * 64;
    const u16* wbase = Wq2 + kc*8192;
    #pragma unroll
    for (int it = 0; it < 4; ++it){
      int t = tbse[it] + k;
      const u16* ga = (vm[it] && t >= 0 && t < TT)
                      ? xg + basen + (size_t)(t*VV + vr[it])*OO + i0
                      : zbuf;
      async16(ga, (char*)A_lds + it*4096 + tid16);
      async16(wbase + ((it*32 + rlow)*64 + gsrc*8), (char*)B_lds + it*4096 + tid16);
    }
    __syncthreads();
    #pragma unroll
    for (int ks = 0; ks < 2; ++ks){
      int p = ((ks*4 + lq) ^ (lane & 7)) * 8;
      s8v af[4], bf[4];
      #pragma unroll
      for (int mi = 0; mi < 4; ++mi)
        af[mi] = *(const s8v*)&A_lds[(wm + mi*16 + lr)*64 + p];
      #pragma unroll
      for (int ni = 0; ni < 4; ++ni)
        bf[ni] = *(const s8v*)&B_lds[(wo + ni*16 + lr)*64 + p];
      #pragma unroll
      for (int mi = 0; mi < 4; ++mi)
        #pragma unroll
        for (int ni = 0; ni < 4; ++ni)
          acc[mi][ni] = __builtin_amdgcn_mfma_f32_16x16x32_bf16(af[mi], bf[ni], acc[mi][ni], 0, 0, 0);
    }
    __syncthreads();
  }

  float bias[4];
  #pragma unroll
  for (int ni = 0; ni < 4; ++ni) bias[ni] = tb[wo + ni*16 + lr];
  float sni[4] = {0.f,0.f,0.f,0.f}, qni[4] = {0.f,0.f,0.f,0.f};
  #pragma unroll
  for (int mi = 0; mi < 4; ++mi){
    int mr = m0 + wm + mi*16 + lq*4;
    #pragma unroll
    for (int ni = 0; ni < 4; ++ni){
      int o = wo + ni*16 + lr;
      #pragma unroll
      for (int rg = 0; rg < 4; ++rg){
        int m = mr + rg;
        if (m < M2){
          float val = acc[mi][ni][rg] + bias[ni];
          xt[((size_t)n*M2 + m)*OO + o] = f2b(val);
          sni[ni] += val;
          qni[ni] += val*val;
        }
      }
    }
  }
  // cross-lq reduce (lanes differ by 16/32), then cross-wave combine via LDS
  #pragma unroll
  for (int ni = 0; ni < 4; ++ni){
    float s = sni[ni], q = qni[ni];
    s += __shfl_xor(s, 16); s += __shfl_xor(s, 32);
    q += __shfl_xor(q, 16); q += __shfl_xor(q, 32);
    if (lane < 16){
      sredS[wv][ni*16 + lane] = s;
      sredQ[wv][ni*16 + lane] = q;
    }
  }
  __syncthreads();
  if (tid < 128){
    int o = tid, base = (o >> 6)*2, lo = o & 63;
    psum[(size_t)bx*128 + o] = sredS[base][lo] + sredS[base+1][lo];
  } else {
    int o = tid - 128, base = (o >> 6)*2, lo = o & 63;
    psq [(size_t)bx*128 + o] = sredQ[base][lo] + sredQ[base+1][lo];
  }
}

// ---------------- BN stats finalize: reduce 960 partials ----------------
__global__ __launch_bounds__(256) void k_stats2(const float* __restrict__ psum, const float* __restrict__ psq,
                                                const float* __restrict__ gamma, const float* __restrict__ beta,
                                                float* __restrict__ stats){
  __shared__ float bufS[256], bufQ[256];
  int tid = threadIdx.x;
  int o = tid & 127, h = tid >> 7;
  float s = 0.f, q = 0.f;
  for (int b = h; b < NB*30; b += 2){ s += psum[(size_t)b*128 + o]; q += psq[(size_t)b*128 + o]; }
  bufS[tid] = s; bufQ[tid] = q;
  __syncthreads();
  if (tid < 128){
    s = bufS[tid] + bufS[tid + 128];
    q = bufQ[tid] + bufQ[tid + 128];
    const float inv = 1.f / 120000.f;
    float mean = s * inv;
    float var  = q * inv - mean*mean;
    float sc = gamma[o] * rsqrtf(var + 1e-5f);
    stats[o]       = sc;
    stats[128 + o] = beta[o] - mean * sc;
  }
}

// ---------------- res as MFMA implicit GEMM + BN + relu: M=(t2*25+v), N=128 o, K=64 c ----------------
// out[n][o][m] with m = t2*25+v  (== reference (N,O,T2,V))
__global__ __launch_bounds__(256, 4) void k_resm(const float* __restrict__ x, const u16* __restrict__ rwb,
                                                 const float* __restrict__ rb, const u16* __restrict__ xt,
                                                 const float* __restrict__ stats, float* __restrict__ out){
  __shared__ __align__(16) u16 A_lds[128*64];   // 16 KB
  __shared__ __align__(16) u16 B_lds[128*64];   // 16 KB
  int bx = blockIdx.x;
  int n  = bx / 30;
  int m0 = (bx % 30) * 128;
  int t20 = m0 / VV, r0 = m0 % VV;
  int tid = threadIdx.x;
  int lane = tid & 63, wv = tid >> 6;
  int wm = (wv & 1) * 64, wo = (wv >> 1) * 64;
  int lr = lane & 15, lq = lane >> 4;

  {
    const u32* g32 = (const u32*)rwb;
    u32* b32 = (u32*)B_lds;
    for (int s = tid; s < 4096; s += 256){
      int row = s >> 5, col = s & 31;
      int g = col >> 2, c2 = col & 3;
      b32[row*32 + ((g ^ (row & 7))*4 + c2)] = g32[s];
    }
  }

  // stage A: tasks (cg, t2i, v): 8 c's packed into one ds_write_b128
  for (int task = tid; task < 8*7*VV; task += 256){
    int cg  = task / (7*VV);
    int rem = task - cg*(7*VV);
    int t2i = rem / VV, v = rem - t2i*VV;
    int t2 = t20 + t2i;
    int ml = t2i*VV + v - r0;
    if (ml >= 0 && ml < 128){
      u16 pk[8];
      if (t2 < TO){
        const float* xp = x + ((size_t)(n*CC + cg*8)*TT + 2*t2)*VV + v;
        #pragma unroll
        for (int cc = 0; cc < 8; ++cc) pk[cc] = f2b(xp[(size_t)cc*(TT*VV)]);
      } else {
        #pragma unroll
        for (int cc = 0; cc < 8; ++cc) pk[cc] = 0;
      }
      *(h8v*)&A_lds[ml*64 + ((cg ^ (ml & 7))*8)] = *(h8v*)pk;
    }
  }
  __syncthreads();

  f4v acc[4][4];
  #pragma unroll
  for (int mi = 0; mi < 4; ++mi)
    #pragma unroll
    for (int ni = 0; ni < 4; ++ni) acc[mi][ni] = (f4v)(0.f);
  #pragma unroll
  for (int ks = 0; ks < 2; ++ks){
    int p = ((ks*4 + lq) ^ (lane & 7)) * 8;
    s8v af[4], bf[4];
    #pragma unroll
    for (int mi = 0; mi < 4; ++mi)
      af[mi] = *(const s8v*)&A_lds[(wm + mi*16 + lr)*64 + p];
    #pragma unroll
    for (int ni = 0; ni < 4; ++ni)
      bf[ni] = *(const s8v*)&B_lds[(wo + ni*16 + lr)*64 + p];
    #pragma unroll
    for (int mi = 0; mi < 4; ++mi)
      #pragma unroll
      for (int ni = 0; ni < 4; ++ni)
        acc[mi][ni] = __builtin_amdgcn_mfma_f32_16x16x32_bf16(af[mi], bf[ni], acc[mi][ni], 0, 0, 0);
  }

  float sc[4], sb[4], rr[4];
  #pragma unroll
  for (int ni = 0; ni < 4; ++ni){
    int o = wo + ni*16 + lr;
    sc[ni] = stats[o]; sb[ni] = stats[128 + o]; rr[ni] = rb[o];
  }
  #pragma unroll
  for (int mi = 0; mi < 4; ++mi){
    int mb = m0 + wm + mi*16 + lq*4;
    #pragma unroll
    for (int ni = 0; ni < 4; ++ni){
      int o = wo + ni*16 + lr;
      size_t xb = ((size_t)n*M2 + mb)*OO + o;
      size_t ob = ((size_t)(n*OO + o))*M2 + mb;
      if (mb + 3 < M2){
        float r0_ = fmaxf(sc[ni]*b2f(xt[xb])        + sb[ni] + acc[mi][ni][0] + rr[ni], 0.f);
        float r1_ = fmaxf(sc[ni]*b2f(xt[xb + OO])   + sb[ni] + acc[mi][ni][1] + rr[ni], 0.f);
        float r2_ = fmaxf(sc[ni]*b2f(xt[xb + 2*OO]) + sb[ni] + acc[mi][ni][2] + rr[ni], 0.f);
        float r3_ = fmaxf(sc[ni]*b2f(xt[xb + 3*OO]) + sb[ni] + acc[mi][ni][3] + rr[ni], 0.f);
        *(float2*)&out[ob]     = make_float2(r0_, r1_);
        *(float2*)&out[ob + 2] = make_float2(r2_, r3_);
      } else {
        #pragma unroll
        for (int rg = 0; rg < 4; ++rg){
          int m = mb + rg;
          if (m < M2){
            float r = sc[ni]*b2f(xt[xb + (size_t)rg*OO]) + sb[ni] + acc[mi][ni][rg] + rr[ni];
            out[ob + rg] = fmaxf(r, 0.f);
          }
        }
      }
    }
  }
}

extern "C" void kernel_launch(void* const* d_in, const int* in_sizes, int n_in,
                              void* d_out, int out_size, void* d_ws, size_t ws_size,
                              hipStream_t stream) {
  const float* x     = (const float*)d_in[0];
  const float* Ap    = (const float*)d_in[1];
  const float* ei    = (const float*)d_in[2];
  const float* gw    = (const float*)d_in[3];
  const float* gb    = (const float*)d_in[4];
  const float* tw    = (const float*)d_in[5];
  const float* tb    = (const float*)d_in[6];
  const float* gamma = (const float*)d_in[7];
  const float* beta  = (const float*)d_in[8];
  const float* rw    = (const float*)d_in[9];
  const float* rb    = (const float*)d_in[10];
  float* out = (float*)d_out;

  char* ws = (char*)d_ws;
  float* Asum  = (float*)ws;                      // 2500 B
  float* zbuf  = (float*)(ws + 2560);             // 512 B zero page
  u16*   Wq2   = (u16*)(ws + 4096);               // 294912 B -> 299008
  u16*   gwb   = (u16*)(ws + 299008);             // 16384 B  -> 315392
  u16*   rwb   = (u16*)(ws + 315392);             // 16384 B  -> 331776
  float* stats = (float*)(ws + 331776);           // 1024 B   -> 332800
  float* psum  = (float*)(ws + 333824);           // 491520 B -> 825344
  float* psq   = (float*)(ws + 825344);           // 491520 B -> 1316864
  u16*   xg    = (u16*)(ws + (2u<<20));           // 61,440,000 B [n][m=t*25+v][o] bf16
  u16*   xt    = (u16*)(ws + 63537152);           // 28,800,000 B [n][m=t2*25+v][o] bf16 (~92.3 MB total)

  k_prep  <<<dim3(644),    dim3(256), 0, stream>>>(Ap, ei, tw, gw, rw, Asum, zbuf, Wq2, gwb, rwb);
  k_gcnm  <<<dim3(NB*MT),  dim3(256), 0, stream>>>(x, Asum, gwb, gb, xg);
  k_tcnm  <<<dim3(NB*30),  dim3(256), 0, stream>>>(xg, Wq2, tb, (const u16*)zbuf, xt, psum, psq);
  k_stats2<<<dim3(1),      dim3(256), 0, stream>>>(psum, psq, gamma, beta, stats);
  k_resm  <<<dim3(NB*30),  dim3(256), 0, stream>>>(x, rwb, rb, xt, stats, out);
}

// Round 11
// 278.862 us; speedup vs baseline: 1.4132x; 1.4132x over previous
//
#include <hip/hip_runtime.h>
#include <hip/hip_bf16.h>

typedef unsigned short u16;
typedef unsigned int   u32;

#define NB 32
#define CC 64
#define TT 300
#define VV 25
#define OO 128
#define TO 150
#define KT 9
#define MM 7500          // T*V rows per n (gcn GEMM)
#define MT 59            // ceil(7500/128)
#define M2 3750          // T2*V rows per n (tcn/res GEMMs)

typedef short s8v  __attribute__((ext_vector_type(8)));
typedef float f4v  __attribute__((ext_vector_type(4)));
typedef u16  h4v  __attribute__((ext_vector_type(4)));
typedef u16  h8v  __attribute__((ext_vector_type(8)));

__device__ __forceinline__ float b2f(u16 u){
  union { u32 i; float f; } c; c.i = ((u32)u) << 16; return c.f;
}
__device__ __forceinline__ u16 f2b(float f){
  __hip_bfloat16 h = __float2bfloat16(f);
  return *reinterpret_cast<u16*>(&h);
}
__device__ __forceinline__ void async16(const void* g, void* l){
  __builtin_amdgcn_global_load_lds((const __attribute__((address_space(1))) u32*)g,
                                   (__attribute__((address_space(3))) u32*)l, 16, 0, 0);
}

// ---------------- prep: A_sum + zero-page + tcn_w repack + gcn_w/res_w bf16 ----------------
__global__ __launch_bounds__(256) void k_prep(const float* __restrict__ Ap, const float* __restrict__ ei,
                                              const float* __restrict__ tw, const float* __restrict__ gw,
                                              const float* __restrict__ rw,
                                              float* __restrict__ Asum, float* __restrict__ zbuf,
                                              u16* __restrict__ Wq2, u16* __restrict__ gwb,
                                              u16* __restrict__ rwb){
  int idx = blockIdx.x * 256 + threadIdx.x;
  if (idx < VV*VV){
    float s = 0.f;
    for (int p = 0; p < 3; ++p) s += ei[p] * Ap[p*VV*VV + idx];
    Asum[idx] = s;
  }
  if (idx >= 640 && idx < 768) zbuf[idx - 640] = 0.f;   // 512 B zero page
  int w = idx - 1024;
  if (w >= 0 && w < 18*OO*64){
    int kc = w >> 13;
    int r  = w & 8191;
    int o  = r >> 6;
    int j  = r & 63;
    int k  = kc >> 1;
    int i  = (kc & 1)*64 + j;
    Wq2[w] = f2b(tw[o*(OO*KT) + i*KT + k]);   // Wq2[kc][o][j] = tcn_w[o][i][k]
  }
  int w2 = idx - 148480;
  if (w2 >= 0 && w2 < OO*CC) gwb[w2] = f2b(gw[w2]);   // gwb[o][c]
  int w3 = idx - 156672;
  if (w3 >= 0 && w3 < OO*CC) rwb[w3] = f2b(rw[w3]);   // rwb[o][c]
}

// ---------------- gcn: register-direct MFMA agg + MFMA GEMM: M=(t*25+v), N=128 o, K=64 c ----------------
// xg layout: [n][m=t*25+v][o].  LDS = 32 KB; no x staging buffer.
__global__ __launch_bounds__(256, 4) void k_gcnm(const float* __restrict__ x, const float* __restrict__ Asum,
                                                 const u16* __restrict__ gwb, const float* __restrict__ gb,
                                                 u16* __restrict__ xg){
  __shared__ __align__(16) u16 A_lds[128*64];   // 16 KB, XOR-swizzled granules
  __shared__ __align__(16) u16 B_lds[128*64];   // 16 KB, XOR-swizzled granules
  int bx = blockIdx.x;
  int n  = bx / MT;
  int m0 = (bx % MT) * 128;
  int t0 = m0 / VV, r0 = m0 % VV;
  int tid = threadIdx.x;
  int lane = tid & 63, wv = tid >> 6;
  int wm = (wv & 1) * 64, wo = (wv >> 1) * 64;
  int lr = lane & 15, lq = lane >> 4;

  // ---- stage B (gwb, 16 KB) with plain coalesced loads + swizzled ds_write ----
  {
    const u32* g32 = (const u32*)gwb;
    u32* b32 = (u32*)B_lds;
    for (int s = tid; s < 4096; s += 256){
      int row = s >> 5, col = s & 31;
      int g = col >> 2, c2 = col & 3;
      b32[row*32 + ((g ^ (row & 7))*4 + c2)] = g32[s];
    }
  }

  // ---- A_sum^T B-fragments in registers: bfw[wt], lane holds B[w=lr+16wt][v=lq*8+j] ----
  s8v bfw[2];
  #pragma unroll
  for (int wt = 0; wt < 2; ++wt){
    u16 tmp[8];
    int w = lr + 16*wt;
    #pragma unroll
    for (int j = 0; j < 8; ++j){
      int v = lq*8 + j;
      tmp[j] = (w < VV && v < VV) ? f2b(Asum[v*VV + w]) : (u16)0;
    }
    bfw[wt] = *(s8v*)tmp;
  }

  // ---- agg via MFMA with register-direct A: 28 tasks (7 it x 4 ct) over 4 waves ----
  #pragma unroll
  for (int tt = 0; tt < 7; ++tt){
    int tau = tt*4 + wv;
    int it = tau >> 2, ct = tau & 3;
    int t  = t0 + it;
    int c  = ct*16 + lr;
    const float* xp = x + ((size_t)(n*CC + c)*TT + t)*VV + lq*8;
    float4 xa = make_float4(0.f,0.f,0.f,0.f), xb = xa;
    float x24 = 0.f;
    if (t < TT){
      if (lq < 3){
        xa = *(const float4*)xp;
        xb = *(const float4*)(xp + 4);
      } else {
        x24 = xp[0];
      }
    }
    u16 pk[8];
    if (lq < 3){
      pk[0]=f2b(xa.x); pk[1]=f2b(xa.y); pk[2]=f2b(xa.z); pk[3]=f2b(xa.w);
      pk[4]=f2b(xb.x); pk[5]=f2b(xb.y); pk[6]=f2b(xb.z); pk[7]=f2b(xb.w);
    } else {
      pk[0]=f2b(x24); pk[1]=0; pk[2]=0; pk[3]=0; pk[4]=0; pk[5]=0; pk[6]=0; pk[7]=0;
    }
    s8v af = *(s8v*)pk;
    f4v d0 = (f4v)(0.f), d1 = (f4v)(0.f);
    d0 = __builtin_amdgcn_mfma_f32_16x16x32_bf16(af, bfw[0], d0, 0, 0, 0);
    d1 = __builtin_amdgcn_mfma_f32_16x16x32_bf16(af, bfw[1], d1, 0, 0, 0);
    int cb = ct*16 + lq*4;
    int g  = cb >> 3, co = cb & 7;
    int ml0 = it*VV + lr - r0;                    // w = lr
    if (ml0 >= 0 && ml0 < 128){
      u16 q[4];
      #pragma unroll
      for (int rg = 0; rg < 4; ++rg) q[rg] = f2b(d0[rg]);
      *(h4v*)&A_lds[ml0*64 + ((g ^ (ml0 & 7))*8) + co] = *(h4v*)q;
    }
    int w1 = lr + 16;
    int ml1 = it*VV + w1 - r0;
    if (w1 < VV && ml1 >= 0 && ml1 < 128){
      u16 q[4];
      #pragma unroll
      for (int rg = 0; rg < 4; ++rg) q[rg] = f2b(d1[rg]);
      *(h4v*)&A_lds[ml1*64 + ((g ^ (ml1 & 7))*8) + co] = *(h4v*)q;
    }
  }
  __syncthreads();

  // ---- main GEMM: 64m x 64o per wave, K=64 (2 substeps) ----
  f4v acc[4][4];
  #pragma unroll
  for (int mi = 0; mi < 4; ++mi)
    #pragma unroll
    for (int ni = 0; ni < 4; ++ni) acc[mi][ni] = (f4v)(0.f);
  #pragma unroll
  for (int ks = 0; ks < 2; ++ks){
    int p = ((ks*4 + lq) ^ (lane & 7)) * 8;
    s8v af[4], bf[4];
    #pragma unroll
    for (int mi = 0; mi < 4; ++mi)
      af[mi] = *(const s8v*)&A_lds[(wm + mi*16 + lr)*64 + p];
    #pragma unroll
    for (int ni = 0; ni < 4; ++ni)
      bf[ni] = *(const s8v*)&B_lds[(wo + ni*16 + lr)*64 + p];
    #pragma unroll
    for (int mi = 0; mi < 4; ++mi)
      #pragma unroll
      for (int ni = 0; ni < 4; ++ni)
        acc[mi][ni] = __builtin_amdgcn_mfma_f32_16x16x32_bf16(af[mi], bf[ni], acc[mi][ni], 0, 0, 0);
  }

  float bias[4];
  #pragma unroll
  for (int ni = 0; ni < 4; ++ni) bias[ni] = gb[wo + ni*16 + lr];
  #pragma unroll
  for (int mi = 0; mi < 4; ++mi){
    int mr = m0 + wm + mi*16 + lq*4;
    #pragma unroll
    for (int ni = 0; ni < 4; ++ni){
      int o = wo + ni*16 + lr;
      #pragma unroll
      for (int rg = 0; rg < 4; ++rg){
        int m = mr + rg;
        if (m < MM)
          xg[((size_t)n*MM + m)*OO + o] = f2b(acc[mi][ni][rg] + bias[ni]);
      }
    }
  }
}

// ---------------- tcn as MFMA implicit GEMM + fused BN partial stats ----------------
// xt layout: [n][m=t2*25+v][o]; psum/psq[bx][128] partial sums (f32, pre-rounding values)
__global__ __launch_bounds__(256) void k_tcnm(const u16* __restrict__ xg, const u16* __restrict__ Wq2,
                                              const float* __restrict__ tb, const u16* __restrict__ zbuf,
                                              u16* __restrict__ xt, float* __restrict__ psum,
                                              float* __restrict__ psq){
  __shared__ __align__(16) u16 A_lds[128*64];
  __shared__ __align__(16) u16 B_lds[128*64];
  __shared__ float sredS[4][64];
  __shared__ float sredQ[4][64];
  int bx = blockIdx.x;
  int n  = bx / 30;
  int m0 = (bx % 30) * 128;
  int tid = threadIdx.x;
  int lane = tid & 63, wv = tid >> 6;
  int wm = (wv & 1) * 64, wo = (wv >> 1) * 64;
  int lr = lane & 15, lq = lane >> 4;

  int rlow = tid >> 3;
  int gsrc = (tid & 7) ^ (rlow & 7);
  int tid16 = tid * 16;
  int  tbse[4], vr[4]; bool vm[4];
  #pragma unroll
  for (int it = 0; it < 4; ++it){
    int m = m0 + it*32 + rlow;
    vm[it] = (m < M2);
    int t2 = m / VV, v = m - t2*VV;
    tbse[it] = 2*t2 - 4;
    vr[it] = v;
  }
  size_t basen = (size_t)n*MM*OO + (size_t)gsrc*8;

  f4v acc[4][4];
  #pragma unroll
  for (int mi = 0; mi < 4; ++mi)
    #pragma unroll
    for (int ni = 0; ni < 4; ++ni) acc[mi][ni] = (f4v)(0.f);

  for (int kc = 0; kc < 18; ++kc){
    int k  = kc >> 1;
    int i0 = (kc & 1) * 64;
    const u16* wbase = Wq2 + kc*8192;
    #pragma unroll
    for (int it = 0; it < 4; ++it){
      int t = tbse[it] + k;
      const u16* ga = (vm[it] && t >= 0 && t < TT)
                      ? xg + basen + (size_t)(t*VV + vr[it])*OO + i0
                      : zbuf;
      async16(ga, (char*)A_lds + it*4096 + tid16);
      async16(wbase + ((it*32 + rlow)*64 + gsrc*8), (char*)B_lds + it*4096 + tid16);
    }
    __syncthreads();
    #pragma unroll
    for (int ks = 0; ks < 2; ++ks){
      int p = ((ks*4 + lq) ^ (lane & 7)) * 8;
      s8v af[4], bf[4];
      #pragma unroll
      for (int mi = 0; mi < 4; ++mi)
        af[mi] = *(const s8v*)&A_lds[(wm + mi*16 + lr)*64 + p];
      #pragma unroll
      for (int ni = 0; ni < 4; ++ni)
        bf[ni] = *(const s8v*)&B_lds[(wo + ni*16 + lr)*64 + p];
      #pragma unroll
      for (int mi = 0; mi < 4; ++mi)
        #pragma unroll
        for (int ni = 0; ni < 4; ++ni)
          acc[mi][ni] = __builtin_amdgcn_mfma_f32_16x16x32_bf16(af[mi], bf[ni], acc[mi][ni], 0, 0, 0);
    }
    __syncthreads();
  }

  float bias[4];
  #pragma unroll
  for (int ni = 0; ni < 4; ++ni) bias[ni] = tb[wo + ni*16 + lr];
  float sni[4] = {0.f,0.f,0.f,0.f}, qni[4] = {0.f,0.f,0.f,0.f};
  #pragma unroll
  for (int mi = 0; mi < 4; ++mi){
    int mr = m0 + wm + mi*16 + lq*4;
    #pragma unroll
    for (int ni = 0; ni < 4; ++ni){
      int o = wo + ni*16 + lr;
      #pragma unroll
      for (int rg = 0; rg < 4; ++rg){
        int m = mr + rg;
        if (m < M2){
          float val = acc[mi][ni][rg] + bias[ni];
          xt[((size_t)n*M2 + m)*OO + o] = f2b(val);
          sni[ni] += val;
          qni[ni] += val*val;
        }
      }
    }
  }
  // cross-lq reduce (lanes differ by 16/32), then cross-wave combine via LDS
  #pragma unroll
  for (int ni = 0; ni < 4; ++ni){
    float s = sni[ni], q = qni[ni];
    s += __shfl_xor(s, 16); s += __shfl_xor(s, 32);
    q += __shfl_xor(q, 16); q += __shfl_xor(q, 32);
    if (lane < 16){
      sredS[wv][ni*16 + lane] = s;
      sredQ[wv][ni*16 + lane] = q;
    }
  }
  __syncthreads();
  if (tid < 128){
    int o = tid, base = (o >> 6)*2, lo = o & 63;
    psum[(size_t)bx*128 + o] = sredS[base][lo] + sredS[base+1][lo];
  } else {
    int o = tid - 128, base = (o >> 6)*2, lo = o & 63;
    psq [(size_t)bx*128 + o] = sredQ[base][lo] + sredQ[base+1][lo];
  }
}

// ---------------- BN stats finalize, stage a: 60 blocks reduce 16 partial rows each ----------------
__global__ __launch_bounds__(256) void k_stats2a(const float* __restrict__ psum, const float* __restrict__ psq,
                                                 float* __restrict__ ps2, float* __restrict__ pq2){
  __shared__ float bufS[256], bufQ[256];
  int tid = threadIdx.x, b = blockIdx.x;
  int o = tid & 127, h = tid >> 7;
  float s = 0.f, q = 0.f;
  for (int r = b*16 + h; r < b*16 + 16; r += 2){
    s += psum[(size_t)r*128 + o];
    q += psq [(size_t)r*128 + o];
  }
  bufS[tid] = s; bufQ[tid] = q;
  __syncthreads();
  if (tid < 128){
    ps2[(size_t)b*128 + o] = bufS[tid] + bufS[tid + 128];
    pq2[(size_t)b*128 + o] = bufQ[tid] + bufQ[tid + 128];
  }
}

// ---------------- BN stats finalize, stage b: reduce 60 level-2 rows ----------------
__global__ __launch_bounds__(256) void k_stats2b(const float* __restrict__ ps2, const float* __restrict__ pq2,
                                                 const float* __restrict__ gamma, const float* __restrict__ beta,
                                                 float* __restrict__ stats){
  __shared__ float bufS[256], bufQ[256];
  int tid = threadIdx.x;
  int o = tid & 127, h = tid >> 7;
  float s = 0.f, q = 0.f;
  for (int b = h; b < 60; b += 2){
    s += ps2[(size_t)b*128 + o];
    q += pq2[(size_t)b*128 + o];
  }
  bufS[tid] = s; bufQ[tid] = q;
  __syncthreads();
  if (tid < 128){
    s = bufS[tid] + bufS[tid + 128];
    q = bufQ[tid] + bufQ[tid + 128];
    const float inv = 1.f / 120000.f;
    float mean = s * inv;
    float var  = q * inv - mean*mean;
    float sc = gamma[o] * rsqrtf(var + 1e-5f);
    stats[o]       = sc;
    stats[128 + o] = beta[o] - mean * sc;
  }
}

// ---------------- res as MFMA implicit GEMM + BN + relu: M=(t2*25+v), N=128 o, K=64 c ----------------
// out[n][o][m] with m = t2*25+v  (== reference (N,O,T2,V))
__global__ __launch_bounds__(256, 4) void k_resm(const float* __restrict__ x, const u16* __restrict__ rwb,
                                                 const float* __restrict__ rb, const u16* __restrict__ xt,
                                                 const float* __restrict__ stats, float* __restrict__ out){
  __shared__ __align__(16) u16 A_lds[128*64];   // 16 KB
  __shared__ __align__(16) u16 B_lds[128*64];   // 16 KB
  int bx = blockIdx.x;
  int n  = bx / 30;
  int m0 = (bx % 30) * 128;
  int t20 = m0 / VV, r0 = m0 % VV;
  int tid = threadIdx.x;
  int lane = tid & 63, wv = tid >> 6;
  int wm = (wv & 1) * 64, wo = (wv >> 1) * 64;
  int lr = lane & 15, lq = lane >> 4;

  {
    const u32* g32 = (const u32*)rwb;
    u32* b32 = (u32*)B_lds;
    for (int s = tid; s < 4096; s += 256){
      int row = s >> 5, col = s & 31;
      int g = col >> 2, c2 = col & 3;
      b32[row*32 + ((g ^ (row & 7))*4 + c2)] = g32[s];
    }
  }

  // stage A: tasks (cg, t2i, v): 8 c's packed into one ds_write_b128
  for (int task = tid; task < 8*7*VV; task += 256){
    int cg  = task / (7*VV);
    int rem = task - cg*(7*VV);
    int t2i = rem / VV, v = rem - t2i*VV;
    int t2 = t20 + t2i;
    int ml = t2i*VV + v - r0;
    if (ml >= 0 && ml < 128){
      u16 pk[8];
      if (t2 < TO){
        const float* xp = x + ((size_t)(n*CC + cg*8)*TT + 2*t2)*VV + v;
        #pragma unroll
        for (int cc = 0; cc < 8; ++cc) pk[cc] = f2b(xp[(size_t)cc*(TT*VV)]);
      } else {
        #pragma unroll
        for (int cc = 0; cc < 8; ++cc) pk[cc] = 0;
      }
      *(h8v*)&A_lds[ml*64 + ((cg ^ (ml & 7))*8)] = *(h8v*)pk;
    }
  }
  __syncthreads();

  f4v acc[4][4];
  #pragma unroll
  for (int mi = 0; mi < 4; ++mi)
    #pragma unroll
    for (int ni = 0; ni < 4; ++ni) acc[mi][ni] = (f4v)(0.f);
  #pragma unroll
  for (int ks = 0; ks < 2; ++ks){
    int p = ((ks*4 + lq) ^ (lane & 7)) * 8;
    s8v af[4], bf[4];
    #pragma unroll
    for (int mi = 0; mi < 4; ++mi)
      af[mi] = *(const s8v*)&A_lds[(wm + mi*16 + lr)*64 + p];
    #pragma unroll
    for (int ni = 0; ni < 4; ++ni)
      bf[ni] = *(const s8v*)&B_lds[(wo + ni*16 + lr)*64 + p];
    #pragma unroll
    for (int mi = 0; mi < 4; ++mi)
      #pragma unroll
      for (int ni = 0; ni < 4; ++ni)
        acc[mi][ni] = __builtin_amdgcn_mfma_f32_16x16x32_bf16(af[mi], bf[ni], acc[mi][ni], 0, 0, 0);
  }

  float sc[4], sb[4], rr[4];
  #pragma unroll
  for (int ni = 0; ni < 4; ++ni){
    int o = wo + ni*16 + lr;
    sc[ni] = stats[o]; sb[ni] = stats[128 + o]; rr[ni] = rb[o];
  }
  #pragma unroll
  for (int mi = 0; mi < 4; ++mi){
    int mb = m0 + wm + mi*16 + lq*4;
    #pragma unroll
    for (int ni = 0; ni < 4; ++ni){
      int o = wo + ni*16 + lr;
      size_t xb = ((size_t)n*M2 + mb)*OO + o;
      size_t ob = ((size_t)(n*OO + o))*M2 + mb;
      if (mb + 3 < M2){
        float r0_ = fmaxf(sc[ni]*b2f(xt[xb])        + sb[ni] + acc[mi][ni][0] + rr[ni], 0.f);
        float r1_ = fmaxf(sc[ni]*b2f(xt[xb + OO])   + sb[ni] + acc[mi][ni][1] + rr[ni], 0.f);
        float r2_ = fmaxf(sc[ni]*b2f(xt[xb + 2*OO]) + sb[ni] + acc[mi][ni][2] + rr[ni], 0.f);
        float r3_ = fmaxf(sc[ni]*b2f(xt[xb + 3*OO]) + sb[ni] + acc[mi][ni][3] + rr[ni], 0.f);
        *(float2*)&out[ob]     = make_float2(r0_, r1_);
        *(float2*)&out[ob + 2] = make_float2(r2_, r3_);
      } else {
        #pragma unroll
        for (int rg = 0; rg < 4; ++rg){
          int m = mb + rg;
          if (m < M2){
            float r = sc[ni]*b2f(xt[xb + (size_t)rg*OO]) + sb[ni] + acc[mi][ni][rg] + rr[ni];
            out[ob + rg] = fmaxf(r, 0.f);
          }
        }
      }
    }
  }
}

extern "C" void kernel_launch(void* const* d_in, const int* in_sizes, int n_in,
                              void* d_out, int out_size, void* d_ws, size_t ws_size,
                              hipStream_t stream) {
  const float* x     = (const float*)d_in[0];
  const float* Ap    = (const float*)d_in[1];
  const float* ei    = (const float*)d_in[2];
  const float* gw    = (const float*)d_in[3];
  const float* gb    = (const float*)d_in[4];
  const float* tw    = (const float*)d_in[5];
  const float* tb    = (const float*)d_in[6];
  const float* gamma = (const float*)d_in[7];
  const float* beta  = (const float*)d_in[8];
  const float* rw    = (const float*)d_in[9];
  const float* rb    = (const float*)d_in[10];
  float* out = (float*)d_out;

  char* ws = (char*)d_ws;
  float* Asum  = (float*)ws;                      // 2500 B
  float* zbuf  = (float*)(ws + 2560);             // 512 B zero page
  u16*   Wq2   = (u16*)(ws + 4096);               // 294912 B -> 299008
  u16*   gwb   = (u16*)(ws + 299008);             // 16384 B  -> 315392
  u16*   rwb   = (u16*)(ws + 315392);             // 16384 B  -> 331776
  float* stats = (float*)(ws + 331776);           // 1024 B   -> 332800
  float* psum  = (float*)(ws + 333824);           // 491520 B -> 825344
  float* psq   = (float*)(ws + 825344);           // 491520 B -> 1316864
  float* ps2   = (float*)(ws + 1316864);          // 30720 B  -> 1347584
  float* pq2   = (float*)(ws + 1347584);          // 30720 B  -> 1378304
  u16*   xg    = (u16*)(ws + (2u<<20));           // 61,440,000 B [n][m=t*25+v][o] bf16
  u16*   xt    = (u16*)(ws + 63537152);           // 28,800,000 B [n][m=t2*25+v][o] bf16 (~92.3 MB total)

  k_prep   <<<dim3(644),    dim3(256), 0, stream>>>(Ap, ei, tw, gw, rw, Asum, zbuf, Wq2, gwb, rwb);
  k_gcnm   <<<dim3(NB*MT),  dim3(256), 0, stream>>>(x, Asum, gwb, gb, xg);
  k_tcnm   <<<dim3(NB*30),  dim3(256), 0, stream>>>(xg, Wq2, tb, (const u16*)zbuf, xt, psum, psq);
  k_stats2a<<<dim3(60),     dim3(256), 0, stream>>>(psum, psq, ps2, pq2);
  k_stats2b<<<dim3(1),      dim3(256), 0, stream>>>(ps2, pq2, gamma, beta, stats);
  k_resm   <<<dim3(NB*30),  dim3(256), 0, stream>>>(x, rwb, rb, xt, stats, out);
}